// Round 7
// baseline (158.475 us; speedup 1.0000x reference)
//
#include <hip/hip_runtime.h>

#define B_  4
#define S_  4096
#define DM  1024
#define DK  64
#define NSPLIT 8
#define KSPAN (S_ / NSPLIT)
#define QT  256                  // queries per flash block
#define PR_ 32                   // proj rows per block

typedef _Float16 half8  __attribute__((ext_vector_type(8)));
typedef _Float16 half4v __attribute__((ext_vector_type(4)));
typedef __fp16   fp16x2 __attribute__((ext_vector_type(2)));   // cvt_pkrtz return type
typedef float    floatx4 __attribute__((ext_vector_type(4)));

// 0.125 (1/sqrt(64)) * log2(e): softmax in exp2 domain
#define QSCALE 0.18033688011112042f
#define EXP2F(x) __builtin_amdgcn_exp2f(x)

// async global->LDS DMA, 16B per lane, wave-uniform LDS base
#define GLOAD16(gsrc, ldst)                                                   \
    __builtin_amdgcn_global_load_lds(                                         \
        (const __attribute__((address_space(1))) void*)(gsrc),                \
        (__attribute__((address_space(3))) void*)(ldst), 16, 0, 0)

// ---------------------------------------------------------------------------
// One-time W transpose+convert: Wt[proj][n][k] f16  <-  W[k][n] fp32.
// ---------------------------------------------------------------------------
__global__ __launch_bounds__(256) void wt_kernel(
    const float* __restrict__ WQ, const float* __restrict__ WK,
    const float* __restrict__ WV, _Float16* __restrict__ Wt)
{
    const int proj = blockIdx.y;
    const float* W = (proj == 0) ? WQ : (proj == 1) ? WK : WV;
    const int k0 = blockIdx.x * 64;
    const int t = threadIdx.x;
    __shared__ float T[64][68];

    #pragma unroll
    for (int p = 0; p < 4; p++) {
        int c = p * 256 + t;
        int k = c >> 4, n4 = (c & 15) * 4;
        float4 v = *(const float4*)(W + (size_t)(k0 + k) * DK + n4);
        T[k][n4 + 0] = v.x; T[k][n4 + 1] = v.y;
        T[k][n4 + 2] = v.z; T[k][n4 + 3] = v.w;
    }
    __syncthreads();

    const int n = t >> 2, kc = (t & 3) * 16;
    half8 h0, h1;
    #pragma unroll
    for (int j = 0; j < 8; j++) h0[j] = (_Float16)T[kc + j][n];
    #pragma unroll
    for (int j = 0; j < 8; j++) h1[j] = (_Float16)T[kc + 8 + j][n];
    _Float16* dst = Wt + ((size_t)proj * 64 + n) * DM + k0 + kc;
    *(half8*)(dst)     = h0;
    *(half8*)(dst + 8) = h1;
}

__device__ inline half4v cvt4_rte(float4 a)
{
    half4v h;
    h[0] = (_Float16)a.x; h[1] = (_Float16)a.y;
    h[2] = (_Float16)a.z; h[3] = (_Float16)a.w;
    return h;
}

// ---------------------------------------------------------------------------
// Proj v5: W staging via global_load_lds DMA (the single change vs v4).
//   v1-v4 all staged W through a VGPR round-trip; v2's counters showed the
//   compiler serializes those loads against register reuse (~150cy each,
//   exposed). global_load_lds has no destination VGPRs: 3 DMA instr/wave/step
//   for W (24 KB linear [192][64] f16), drained by the one barrier AFTER
//   compute. X stays on the tiny reg path (1 float4/thread/step, depth-2
//   prefetch). LDS 57 KB -> 2 blocks/CU. Waves: (m-tile 0..1)x(n-quarter
//   0..3), 16 rows x 48 cols each, 6 MFMA/step.
// ---------------------------------------------------------------------------
__global__ __launch_bounds__(512) void proj_mfma_kernel(
    const float* __restrict__ X, const _Float16* __restrict__ Wt,
    const float* __restrict__ bQ, const float* __restrict__ bK,
    const float* __restrict__ bV,
    _Float16* __restrict__ Qh, _Float16* __restrict__ Kh,
    _Float16* __restrict__ Vt)
{
    const int r0   = blockIdx.x * PR_;
    const int t    = threadIdx.x;
    const int wave = t >> 6, lane = t & 63;
    const int quad = lane >> 4, l15 = lane & 15;
    const int mt   = wave >> 2, nq = wave & 3;   // m-tile, n-quarter

    __shared__ __align__(16) _Float16 Xs[2][PR_ * 72];    //  9 KB (padded, reg-staged)
    __shared__ __align__(16) _Float16 Ws[2][192 * 64];    // 48 KB (linear, DMA-staged)

    // X staging: 32 rows x 64 cols, 16 thr/row, float4 each
    const int xr = t >> 4, xc = (t & 15) * 4;
    const float* xsrc = X + (size_t)(r0 + xr) * DM + xc;

    // W DMA sources: chunk c = p*512 + t -> row p*64 + (t>>3), halves (t&7)*8
    const _Float16* wg0 = Wt + (size_t)(t >> 3) * DM + (t & 7) * 8;
    const _Float16* wg1 = wg0 + (size_t)64 * DM;
    const _Float16* wg2 = wg0 + (size_t)128 * DM;

#define GLOADW(bb, kk)                                                        \
    {                                                                         \
        GLOAD16(wg0 + (kk) * 64, &Ws[bb][0    + wave * 512]);                 \
        GLOAD16(wg1 + (kk) * 64, &Ws[bb][4096 + wave * 512]);                 \
        GLOAD16(wg2 + (kk) * 64, &Ws[bb][8192 + wave * 512]);                 \
    }

    floatx4 acc[3];
    #pragma unroll
    for (int j = 0; j < 3; j++) acc[j] = (floatx4){0.f, 0.f, 0.f, 0.f};

    // prologue: kt=0 into buf0; prefetch X for kt=1
    float4 xreg = *(const float4*)(xsrc);
    GLOADW(0, 0);
    *(half4v*)&Xs[0][xr * 72 + xc] = cvt4_rte(xreg);
    xreg = *(const float4*)(xsrc + 64);
    __syncthreads();                  // W DMA drained + Xs[0] visible

    int cur = 0;
    #pragma unroll
    for (int kt = 0; kt < DM / 64; kt++) {
        if (kt + 1 < DM / 64)         // issue next W tile NOW; lands during
            GLOADW(cur ^ 1, kt + 1);  // this step's compute

        half8 xa0 = *(half8*)&Xs[cur][(mt * 16 + l15) * 72 + quad * 8];
        half8 xa1 = *(half8*)&Xs[cur][(mt * 16 + l15) * 72 + 32 + quad * 8];
        #pragma unroll
        for (int j = 0; j < 3; j++) {
            const int wn = (nq * 3 + j) * 16 + l15;       // flat Wt row
            half8 bf0 = *(half8*)&Ws[cur][wn * 64 + quad * 8];
            half8 bf1 = *(half8*)&Ws[cur][wn * 64 + 32 + quad * 8];
            floatx4 a = acc[j];
            a = __builtin_amdgcn_mfma_f32_16x16x32_f16(xa0, bf0, a, 0, 0, 0);
            a = __builtin_amdgcn_mfma_f32_16x16x32_f16(xa1, bf1, a, 0, 0, 0);
            acc[j] = a;
        }

        if (kt + 1 < DM / 64) {       // X write to other buffer after compute
            *(half4v*)&Xs[cur ^ 1][xr * 72 + xc] = cvt4_rte(xreg);
            if (kt + 2 < DM / 64)
                xreg = *(const float4*)(xsrc + (kt + 2) * 64);
        }
        __syncthreads();              // drains W DMA + X writes -> next ready
        cur ^= 1;
    }
#undef GLOADW

    // epilogue: flat tile f = nq*3+j in 0..11 -> proj = f>>2, nt = f&3
    const int orow = r0 + mt * 16 + quad * 4;
    const int bidx = r0 >> 12;
    const int s0   = (r0 & (S_ - 1)) + mt * 16 + quad * 4;

    #pragma unroll
    for (int j = 0; j < 3; j++) {
        const int f  = nq * 3 + j;
        const int d  = (f & 3) * 16 + l15;
        if ((f >> 2) == 0) {
            const float bq = bQ[d];
            #pragma unroll
            for (int i = 0; i < 4; i++)
                Qh[(size_t)(orow + i) * DK + d] =
                    (_Float16)((acc[j][i] + bq) * QSCALE);
        } else if ((f >> 2) == 1) {
            const float bk = bK[d];
            #pragma unroll
            for (int i = 0; i < 4; i++)
                Kh[(size_t)(orow + i) * DK + d] =
                    (_Float16)(acc[j][i] + bk);
        } else {
            const float bv = bV[d];
            half4v hv;
            #pragma unroll
            for (int i = 0; i < 4; i++)
                hv[i] = (_Float16)(acc[j][i] + bv);
            *(half4v*)(Vt + (size_t)bidx * DK * S_ + (size_t)d * S_ + s0) = hv;
        }
    }
}

// ---------------------------------------------------------------------------
// Flash v5 (unchanged from R3): swapped-operand MFMA + key-permuted K staging
// = in-register P. DS ops/lane/tile 18; LDS 36.9KB.
// ---------------------------------------------------------------------------
__global__ __launch_bounds__(512, 4) void flash_mfma_kernel(
    const _Float16* __restrict__ Qh, const _Float16* __restrict__ Kh,
    const _Float16* __restrict__ Vt, _Float16* __restrict__ Oph,
    float* __restrict__ Lp)
{
    const int b     = blockIdx.y;
    const int q0    = blockIdx.x * QT;
    const int split = blockIdx.z;
    const int kbase = split * KSPAN;
    const int t     = threadIdx.x;
    const int wave  = t >> 6, lane = t & 63;
    const int quad  = lane >> 4, l15 = lane & 15;

    __shared__ __align__(16) _Float16 Ks[2][64 * 72];     // key-permuted rows
    __shared__ __align__(16) _Float16 Vs[2][64 * 72];     // [d][key]

    const _Float16* Qb = Qh + ((size_t)b * S_ + q0) * DK;
    const _Float16* Kb = Kh + ((size_t)b * S_ + kbase) * DK;
    const _Float16* Vb = Vt + (size_t)b * DK * S_ + kbase;

    half8 qf0[2], qf1[2];
    #pragma unroll
    for (int mt = 0; mt < 2; mt++) {
        const _Float16* qr = Qb + (size_t)(wave * 32 + mt * 16 + l15) * DK;
        qf0[mt] = *(const half8*)(qr + quad * 8);
        qf1[mt] = *(const half8*)(qr + 32 + quad * 8);
    }

    floatx4 acc[2][4];
    float rs[2];
    #pragma unroll
    for (int mt = 0; mt < 2; mt++) {
        #pragma unroll
        for (int nt = 0; nt < 4; nt++) acc[mt][nt] = (floatx4){0.f,0.f,0.f,0.f};
        rs[mt] = 0.f;
    }

    const int kr   = t >> 3, kcol = (t & 7) * 8;
    const int krP  = (kr & 32) | ((kr & 4) << 2) | ((kr & 24) >> 1) | (kr & 3);
    half8 kreg = *(const half8*)(Kb + (size_t)kr * DK + kcol);
    half8 vreg = *(const half8*)(Vb + (size_t)kr * S_ + kcol);
    *(half8*)&Ks[0][krP * 72 + kcol] = kreg;
    *(half8*)&Vs[0][kr  * 72 + kcol] = vreg;

    const int NT = KSPAN / 64;
    int cur = 0;
    for (int it = 0; it < NT; it++) {
        __syncthreads();

        if (it + 1 < NT) {
            const int kn = (it + 1) * 64;
            kreg = *(const half8*)(Kb + (size_t)(kn + kr) * DK + kcol);
            vreg = *(const half8*)(Vb + (size_t)kr * S_ + kn + kcol);
        }

        floatx4 sc[2][4];
        __builtin_amdgcn_s_setprio(1);
        #pragma unroll
        for (int nt = 0; nt < 4; nt++) {
            half8 kf0 = *(half8*)&Ks[cur][(nt * 16 + l15) * 72 + quad * 8];
            half8 kf1 = *(half8*)&Ks[cur][(nt * 16 + l15) * 72 + 32 + quad * 8];
            #pragma unroll
            for (int mt = 0; mt < 2; mt++) {
                floatx4 z = (floatx4){0.f, 0.f, 0.f, 0.f};
                z = __builtin_amdgcn_mfma_f32_16x16x32_f16(kf0, qf0[mt], z, 0, 0, 0);
                z = __builtin_amdgcn_mfma_f32_16x16x32_f16(kf1, qf1[mt], z, 0, 0, 0);
                sc[mt][nt] = z;
            }
        }
        __builtin_amdgcn_s_setprio(0);

        half8 pf0[2], pf1[2];
        #pragma unroll
        for (int mt = 0; mt < 2; mt++) {
            float pe[4][4];
            #pragma unroll
            for (int nt = 0; nt < 4; nt++)
                #pragma unroll
                for (int i = 0; i < 4; i++) {
                    pe[nt][i] = EXP2F(sc[mt][nt][i]);
                    rs[mt] += pe[nt][i];
                }
            fp16x2 c0 = __builtin_amdgcn_cvt_pkrtz(pe[0][0], pe[0][1]);
            fp16x2 c1 = __builtin_amdgcn_cvt_pkrtz(pe[0][2], pe[0][3]);
            fp16x2 c2 = __builtin_amdgcn_cvt_pkrtz(pe[1][0], pe[1][1]);
            fp16x2 c3 = __builtin_amdgcn_cvt_pkrtz(pe[1][2], pe[1][3]);
            pf0[mt] = (half8){(_Float16)c0[0], (_Float16)c0[1],
                              (_Float16)c1[0], (_Float16)c1[1],
                              (_Float16)c2[0], (_Float16)c2[1],
                              (_Float16)c3[0], (_Float16)c3[1]};
            fp16x2 c4 = __builtin_amdgcn_cvt_pkrtz(pe[2][0], pe[2][1]);
            fp16x2 c5 = __builtin_amdgcn_cvt_pkrtz(pe[2][2], pe[2][3]);
            fp16x2 c6 = __builtin_amdgcn_cvt_pkrtz(pe[3][0], pe[3][1]);
            fp16x2 c7 = __builtin_amdgcn_cvt_pkrtz(pe[3][2], pe[3][3]);
            pf1[mt] = (half8){(_Float16)c4[0], (_Float16)c4[1],
                              (_Float16)c5[0], (_Float16)c5[1],
                              (_Float16)c6[0], (_Float16)c6[1],
                              (_Float16)c7[0], (_Float16)c7[1]};
        }

        __builtin_amdgcn_s_setprio(1);
        #pragma unroll
        for (int nt = 0; nt < 4; nt++) {
            half8 vf0 = *(half8*)&Vs[cur][(nt * 16 + l15) * 72 + quad * 8];
            half8 vf1 = *(half8*)&Vs[cur][(nt * 16 + l15) * 72 + 32 + quad * 8];
            #pragma unroll
            for (int mt = 0; mt < 2; mt++) {
                floatx4 a = acc[mt][nt];
                a = __builtin_amdgcn_mfma_f32_16x16x32_f16(vf0, pf0[mt], a, 0, 0, 0);
                a = __builtin_amdgcn_mfma_f32_16x16x32_f16(vf1, pf1[mt], a, 0, 0, 0);
                acc[mt][nt] = a;
            }
        }
        __builtin_amdgcn_s_setprio(0);

        if (it + 1 < NT) {
            *(half8*)&Ks[cur ^ 1][krP * 72 + kcol] = kreg;
            *(half8*)&Vs[cur ^ 1][kr  * 72 + kcol] = vreg;
        }
        cur ^= 1;
    }

    const size_t prow = (size_t)split * B_ * S_ + (size_t)b * S_ + q0;
    #pragma unroll
    for (int mt = 0; mt < 2; mt++) {
        float r = rs[mt];
        r += __shfl_xor(r, 16, 64);
        r += __shfl_xor(r, 32, 64);
        const float inv = 1.0f / r;
        const size_t orow = prow + wave * 32 + mt * 16 + l15;
        #pragma unroll
        for (int nt = 0; nt < 4; nt++) {
            half4v hv;
            #pragma unroll
            for (int i = 0; i < 4; i++)
                hv[i] = (_Float16)(acc[mt][nt][i] * inv);
            *(half4v*)(Oph + orow * DK + nt * 16 + quad * 4) = hv;
        }
        if (quad == 0)
            Lp[orow] = r;
    }
}

// ---------------------------------------------------------------------------
// Combine: O[r] = sum_s l_s * Ohat_s[r] / sum_s l_s.  16 rows x 16 lanes.
// ---------------------------------------------------------------------------
__global__ __launch_bounds__(256) void combine_kernel(
    const _Float16* __restrict__ Oph, const float* __restrict__ Lp,
    float* __restrict__ O)
{
    const int r  = blockIdx.x * 16 + (threadIdx.x >> 4);
    const int d4 = (threadIdx.x & 15) * 4;
    const int NR = B_ * S_;

    float lw[NSPLIT], lsum = 0.f;
    #pragma unroll
    for (int s = 0; s < NSPLIT; s++) {
        lw[s] = Lp[(size_t)s * NR + r];
        lsum += lw[s];
    }
    const float inv = 1.0f / lsum;

    float o[4] = {0.f, 0.f, 0.f, 0.f};
    #pragma unroll
    for (int s = 0; s < NSPLIT; s++) {
        half4v h = *(const half4v*)(Oph + ((size_t)s * NR + r) * DK + d4);
        const float w = lw[s];
        #pragma unroll
        for (int j = 0; j < 4; j++) o[j] += w * (float)h[j];
    }
    float4 out;
    out.x = o[0] * inv; out.y = o[1] * inv;
    out.z = o[2] * inv; out.w = o[3] * inv;
    *(float4*)(O + (size_t)r * DK + d4) = out;
}

// ---------------------------------------------------------------------------
extern "C" void kernel_launch(void* const* d_in, const int* in_sizes, int n_in,
                              void* d_out, int out_size, void* d_ws, size_t ws_size,
                              hipStream_t stream)
{
    const float* X  = (const float*)d_in[0];
    // cultural path (d_in[1], d_in[8..10]) cancels in softmax -> unused
    const float* WQ = (const float*)d_in[2];
    const float* bQ = (const float*)d_in[3];
    const float* WK = (const float*)d_in[4];
    const float* bK = (const float*)d_in[5];
    const float* WV = (const float*)d_in[6];
    const float* bV = (const float*)d_in[7];

    char* ws = (char*)d_ws;
    _Float16* Qh  = (_Float16*)ws;  ws += (size_t)B_ * S_ * DK * 2;   // 2 MiB
    _Float16* Kh  = (_Float16*)ws;  ws += (size_t)B_ * S_ * DK * 2;
    _Float16* Vt  = (_Float16*)ws;  ws += (size_t)B_ * S_ * DK * 2;
    _Float16* Wt  = (_Float16*)ws;  ws += (size_t)3 * 64 * DM * 2;    // 384 KiB
    _Float16* Oph = (_Float16*)ws;  ws += (size_t)NSPLIT * B_ * S_ * DK * 2; // 16 MiB
    float* Lp     = (float*)ws;

    wt_kernel<<<dim3(DM / 64, 3), 256, 0, stream>>>(WQ, WK, WV, Wt);

    proj_mfma_kernel<<<dim3((B_ * S_) / PR_), 512, 0, stream>>>(
        X, Wt, bQ, bK, bV, Qh, Kh, Vt);

    flash_mfma_kernel<<<dim3(S_ / QT, B_, NSPLIT), 512, 0, stream>>>(
        Qh, Kh, Vt, Oph, Lp);

    combine_kernel<<<dim3((B_ * S_) / 16), 256, 0, stream>>>(
        Oph, Lp, (float*)d_out);
}

// Round 8
// 153.253 us; speedup vs baseline: 1.0341x; 1.0341x over previous
//
#include <hip/hip_runtime.h>

#define B_  4
#define S_  4096
#define DM  1024
#define DK  64
#define NSPLIT 8
#define KSPAN (S_ / NSPLIT)
#define QT  256                  // queries per flash block

typedef _Float16 half8  __attribute__((ext_vector_type(8)));
typedef _Float16 half4v __attribute__((ext_vector_type(4)));
typedef __fp16   fp16x2 __attribute__((ext_vector_type(2)));   // cvt_pkrtz return type
typedef float    floatx4 __attribute__((ext_vector_type(4)));

// 0.125 (1/sqrt(64)) * log2(e): softmax in exp2 domain
#define QSCALE 0.18033688011112042f
#define EXP2F(x) __builtin_amdgcn_exp2f(x)

// ---------------------------------------------------------------------------
// One-time W transpose+convert: Wt[proj][n][k] f16  <-  W[k][n] fp32.
// ---------------------------------------------------------------------------
__global__ __launch_bounds__(256) void wt_kernel(
    const float* __restrict__ WQ, const float* __restrict__ WK,
    const float* __restrict__ WV, _Float16* __restrict__ Wt)
{
    const int proj = blockIdx.y;
    const float* W = (proj == 0) ? WQ : (proj == 1) ? WK : WV;
    const int k0 = blockIdx.x * 64;
    const int t = threadIdx.x;
    __shared__ float T[64][68];

    #pragma unroll
    for (int p = 0; p < 4; p++) {
        int c = p * 256 + t;
        int k = c >> 4, n4 = (c & 15) * 4;
        float4 v = *(const float4*)(W + (size_t)(k0 + k) * DK + n4);
        T[k][n4 + 0] = v.x; T[k][n4 + 1] = v.y;
        T[k][n4 + 2] = v.z; T[k][n4 + 3] = v.w;
    }
    __syncthreads();

    const int n = t >> 2, kc = (t & 3) * 16;
    half8 h0, h1;
    #pragma unroll
    for (int j = 0; j < 8; j++) h0[j] = (_Float16)T[kc + j][n];
    #pragma unroll
    for (int j = 0; j < 8; j++) h1[j] = (_Float16)T[kc + 8 + j][n];
    _Float16* dst = Wt + ((size_t)proj * 64 + n) * DM + k0 + kc;
    *(half8*)(dst)     = h0;
    *(half8*)(dst + 8) = h1;
}

// ---------------------------------------------------------------------------
// Proj v1 (reverted: best measured of 5 variants, ~31 us). LDS-staged,
// 256 thr / 4 waves, double-barrier per K-step.
// ---------------------------------------------------------------------------
__global__ __launch_bounds__(256) void proj_mfma_kernel(
    const float* __restrict__ X, const _Float16* __restrict__ Wt,
    const float* __restrict__ bQ, const float* __restrict__ bK,
    const float* __restrict__ bV,
    _Float16* __restrict__ Qh, _Float16* __restrict__ Kh,
    _Float16* __restrict__ Vt)
{
    const int r0   = blockIdx.x * 64;
    const int t    = threadIdx.x;
    const int wave = t >> 6, lane = t & 63;
    const int quad = lane >> 4, l15 = lane & 15;

    __shared__ __align__(16) _Float16 Xs[64 * 72];
    __shared__ __align__(16) _Float16 Ws[3][64 * 72];

    floatx4 acc[3][4];
    #pragma unroll
    for (int p = 0; p < 3; p++)
        #pragma unroll
        for (int nt = 0; nt < 4; nt++)
            acc[p][nt] = (floatx4){0.f, 0.f, 0.f, 0.f};

    int xrow[4], xcol[4];
    #pragma unroll
    for (int p = 0; p < 4; p++) {
        int c = p * 256 + t;
        xrow[p] = c >> 4; xcol[p] = (c & 15) * 4;
    }
    int wrow[2], wcol[2];
    #pragma unroll
    for (int p = 0; p < 2; p++) {
        int c = p * 256 + t;
        wrow[p] = c >> 3; wcol[p] = (c & 7) * 8;
    }

    float4 xr[4]; half8 wr[3][2];
    #pragma unroll
    for (int p = 0; p < 4; p++)
        xr[p] = *(const float4*)(X + (size_t)(r0 + xrow[p]) * DM + xcol[p]);
    #pragma unroll
    for (int pr = 0; pr < 3; pr++)
        #pragma unroll
        for (int p = 0; p < 2; p++)
            wr[pr][p] = *(const half8*)(Wt + ((size_t)pr * 64 + wrow[p]) * DM + wcol[p]);

    for (int kt = 0; kt < DM / 64; kt++) {
        __syncthreads();
        #pragma unroll
        for (int p = 0; p < 4; p++) {
            half4v h;
            h[0] = (_Float16)xr[p].x; h[1] = (_Float16)xr[p].y;
            h[2] = (_Float16)xr[p].z; h[3] = (_Float16)xr[p].w;
            *(half4v*)&Xs[xrow[p] * 72 + xcol[p]] = h;
        }
        #pragma unroll
        for (int pr = 0; pr < 3; pr++)
            #pragma unroll
            for (int p = 0; p < 2; p++)
                *(half8*)&Ws[pr][wrow[p] * 72 + wcol[p]] = wr[pr][p];
        __syncthreads();

        if (kt + 1 < DM / 64) {
            const int kn = (kt + 1) * 64;
            #pragma unroll
            for (int p = 0; p < 4; p++)
                xr[p] = *(const float4*)(X + (size_t)(r0 + xrow[p]) * DM + kn + xcol[p]);
            #pragma unroll
            for (int pr = 0; pr < 3; pr++)
                #pragma unroll
                for (int p = 0; p < 2; p++)
                    wr[pr][p] = *(const half8*)(Wt + ((size_t)pr * 64 + wrow[p]) * DM + kn + wcol[p]);
        }

        half8 xa0 = *(half8*)&Xs[(wave * 16 + l15) * 72 + quad * 8];
        half8 xa1 = *(half8*)&Xs[(wave * 16 + l15) * 72 + 32 + quad * 8];
        #pragma unroll
        for (int pr = 0; pr < 3; pr++) {
            #pragma unroll
            for (int nt = 0; nt < 4; nt++) {
                half8 bf0 = *(half8*)&Ws[pr][(nt * 16 + l15) * 72 + quad * 8];
                half8 bf1 = *(half8*)&Ws[pr][(nt * 16 + l15) * 72 + 32 + quad * 8];
                floatx4 a = acc[pr][nt];
                a = __builtin_amdgcn_mfma_f32_16x16x32_f16(xa0, bf0, a, 0, 0, 0);
                a = __builtin_amdgcn_mfma_f32_16x16x32_f16(xa1, bf1, a, 0, 0, 0);
                acc[pr][nt] = a;
            }
        }
    }

    float bqv[4], bkv[4], bvv[4];
    #pragma unroll
    for (int nt = 0; nt < 4; nt++) {
        bqv[nt] = bQ[nt * 16 + l15];
        bkv[nt] = bK[nt * 16 + l15];
        bvv[nt] = bV[nt * 16 + l15];
    }

    const int orow = r0 + wave * 16 + quad * 4;
    const int bidx = r0 >> 12;
    const int s0   = (r0 & (S_ - 1)) + wave * 16 + quad * 4;
    #pragma unroll
    for (int nt = 0; nt < 4; nt++) {
        const int d = nt * 16 + l15;
        #pragma unroll
        for (int i = 0; i < 4; i++) {
            Qh[(size_t)(orow + i) * DK + d] =
                (_Float16)((acc[0][nt][i] + bqv[nt]) * QSCALE);
            Kh[(size_t)(orow + i) * DK + d] =
                (_Float16)(acc[1][nt][i] + bkv[nt]);
        }
        half4v hv;
        #pragma unroll
        for (int i = 0; i < 4; i++)
            hv[i] = (_Float16)(acc[2][nt][i] + bvv[nt]);
        *(half4v*)(Vt + (size_t)bidx * DK * S_ + (size_t)d * S_ + s0) = hv;
    }
}

// ---------------------------------------------------------------------------
// Flash v6: register-slimmed v5. exp2+cvt_pkrtz fused INTO the QK nt-loop so
// sc[2][4] (32 VGPR) and pe[4][4] (16 VGPR) never materialize -> peak live
// ~100 VGPR < the launch_bounds(512,4) cap of 128 -> no scratch spills at
// 2 blocks/CU. setprio removed (lockstep 8-wave block: m190 regime).
// Math order of rs/pf identical to v5 (bitwise-same outputs).
// ---------------------------------------------------------------------------
__global__ __launch_bounds__(512, 4) void flash_mfma_kernel(
    const _Float16* __restrict__ Qh, const _Float16* __restrict__ Kh,
    const _Float16* __restrict__ Vt, _Float16* __restrict__ Oph,
    float* __restrict__ Lp)
{
    const int b     = blockIdx.y;
    const int q0    = blockIdx.x * QT;
    const int split = blockIdx.z;
    const int kbase = split * KSPAN;
    const int t     = threadIdx.x;
    const int wave  = t >> 6, lane = t & 63;
    const int quad  = lane >> 4, l15 = lane & 15;

    __shared__ __align__(16) _Float16 Ks[2][64 * 72];     // key-permuted rows
    __shared__ __align__(16) _Float16 Vs[2][64 * 72];     // [d][key]

    const _Float16* Qb = Qh + ((size_t)b * S_ + q0) * DK;
    const _Float16* Kb = Kh + ((size_t)b * S_ + kbase) * DK;
    const _Float16* Vb = Vt + (size_t)b * DK * S_ + kbase;

    half8 qf0[2], qf1[2];
    #pragma unroll
    for (int mt = 0; mt < 2; mt++) {
        const _Float16* qr = Qb + (size_t)(wave * 32 + mt * 16 + l15) * DK;
        qf0[mt] = *(const half8*)(qr + quad * 8);
        qf1[mt] = *(const half8*)(qr + 32 + quad * 8);
    }

    floatx4 acc[2][4];
    float rs[2];
    #pragma unroll
    for (int mt = 0; mt < 2; mt++) {
        #pragma unroll
        for (int nt = 0; nt < 4; nt++) acc[mt][nt] = (floatx4){0.f,0.f,0.f,0.f};
        rs[mt] = 0.f;
    }

    const int kr   = t >> 3, kcol = (t & 7) * 8;
    const int krP  = (kr & 32) | ((kr & 4) << 2) | ((kr & 24) >> 1) | (kr & 3);
    half8 kreg = *(const half8*)(Kb + (size_t)kr * DK + kcol);
    half8 vreg = *(const half8*)(Vb + (size_t)kr * S_ + kcol);
    *(half8*)&Ks[0][krP * 72 + kcol] = kreg;
    *(half8*)&Vs[0][kr  * 72 + kcol] = vreg;

    const int NT = KSPAN / 64;
    int cur = 0;
    for (int it = 0; it < NT; it++) {
        __syncthreads();     // buf[cur] ready; everyone done with buf[cur^1]

        if (it + 1 < NT) {
            const int kn = (it + 1) * 64;
            kreg = *(const half8*)(Kb + (size_t)(kn + kr) * DK + kcol);
            vreg = *(const half8*)(Vb + (size_t)kr * S_ + kn + kcol);
        }

        // QK^T fused with softmax numerator: each z consumed immediately
        // (exp2 -> rowsum -> pack into P^T fragment slot). No sc/pe arrays.
        half8 pf0[2], pf1[2];
        #pragma unroll
        for (int nt = 0; nt < 4; nt++) {
            half8 kf0 = *(half8*)&Ks[cur][(nt * 16 + l15) * 72 + quad * 8];
            half8 kf1 = *(half8*)&Ks[cur][(nt * 16 + l15) * 72 + 32 + quad * 8];
            #pragma unroll
            for (int mt = 0; mt < 2; mt++) {
                floatx4 z = (floatx4){0.f, 0.f, 0.f, 0.f};
                z = __builtin_amdgcn_mfma_f32_16x16x32_f16(kf0, qf0[mt], z, 0, 0, 0);
                z = __builtin_amdgcn_mfma_f32_16x16x32_f16(kf1, qf1[mt], z, 0, 0, 0);
                float p0 = EXP2F(z[0]), p1 = EXP2F(z[1]);
                float p2 = EXP2F(z[2]), p3 = EXP2F(z[3]);
                rs[mt] += p0; rs[mt] += p1; rs[mt] += p2; rs[mt] += p3;
                fp16x2 ca = __builtin_amdgcn_cvt_pkrtz(p0, p1);
                fp16x2 cb = __builtin_amdgcn_cvt_pkrtz(p2, p3);
                if (nt < 2) {
                    pf0[mt][(nt & 1) * 4 + 0] = (_Float16)ca[0];
                    pf0[mt][(nt & 1) * 4 + 1] = (_Float16)ca[1];
                    pf0[mt][(nt & 1) * 4 + 2] = (_Float16)cb[0];
                    pf0[mt][(nt & 1) * 4 + 3] = (_Float16)cb[1];
                } else {
                    pf1[mt][(nt & 1) * 4 + 0] = (_Float16)ca[0];
                    pf1[mt][(nt & 1) * 4 + 1] = (_Float16)ca[1];
                    pf1[mt][(nt & 1) * 4 + 2] = (_Float16)cb[0];
                    pf1[mt][(nt & 1) * 4 + 3] = (_Float16)cb[1];
                }
            }
        }

        // O^T += V^T·P^T
        #pragma unroll
        for (int nt = 0; nt < 4; nt++) {
            half8 vf0 = *(half8*)&Vs[cur][(nt * 16 + l15) * 72 + quad * 8];
            half8 vf1 = *(half8*)&Vs[cur][(nt * 16 + l15) * 72 + 32 + quad * 8];
            #pragma unroll
            for (int mt = 0; mt < 2; mt++) {
                floatx4 a = acc[mt][nt];
                a = __builtin_amdgcn_mfma_f32_16x16x32_f16(vf0, pf0[mt], a, 0, 0, 0);
                a = __builtin_amdgcn_mfma_f32_16x16x32_f16(vf1, pf1[mt], a, 0, 0, 0);
                acc[mt][nt] = a;
            }
        }

        if (it + 1 < NT) {
            *(half8*)&Ks[cur ^ 1][krP * 72 + kcol] = kreg;
            *(half8*)&Vs[cur ^ 1][kr  * 72 + kcol] = vreg;
        }
        cur ^= 1;
    }

    const size_t prow = (size_t)split * B_ * S_ + (size_t)b * S_ + q0;
    #pragma unroll
    for (int mt = 0; mt < 2; mt++) {
        float r = rs[mt];
        r += __shfl_xor(r, 16, 64);
        r += __shfl_xor(r, 32, 64);
        const float inv = 1.0f / r;
        const size_t orow = prow + wave * 32 + mt * 16 + l15;
        #pragma unroll
        for (int nt = 0; nt < 4; nt++) {
            half4v hv;
            #pragma unroll
            for (int i = 0; i < 4; i++)
                hv[i] = (_Float16)(acc[mt][nt][i] * inv);
            *(half4v*)(Oph + orow * DK + nt * 16 + quad * 4) = hv;
        }
        if (quad == 0)
            Lp[orow] = r;
    }
}

// ---------------------------------------------------------------------------
// Combine: O[r] = sum_s l_s * Ohat_s[r] / sum_s l_s.  16 rows x 16 lanes.
// ---------------------------------------------------------------------------
__global__ __launch_bounds__(256) void combine_kernel(
    const _Float16* __restrict__ Oph, const float* __restrict__ Lp,
    float* __restrict__ O)
{
    const int r  = blockIdx.x * 16 + (threadIdx.x >> 4);
    const int d4 = (threadIdx.x & 15) * 4;
    const int NR = B_ * S_;

    float lw[NSPLIT], lsum = 0.f;
    #pragma unroll
    for (int s = 0; s < NSPLIT; s++) {
        lw[s] = Lp[(size_t)s * NR + r];
        lsum += lw[s];
    }
    const float inv = 1.0f / lsum;

    float o[4] = {0.f, 0.f, 0.f, 0.f};
    #pragma unroll
    for (int s = 0; s < NSPLIT; s++) {
        half4v h = *(const half4v*)(Oph + ((size_t)s * NR + r) * DK + d4);
        const float w = lw[s];
        #pragma unroll
        for (int j = 0; j < 4; j++) o[j] += w * (float)h[j];
    }
    float4 out;
    out.x = o[0] * inv; out.y = o[1] * inv;
    out.z = o[2] * inv; out.w = o[3] * inv;
    *(float4*)(O + (size_t)r * DK + d4) = out;
}

// ---------------------------------------------------------------------------
extern "C" void kernel_launch(void* const* d_in, const int* in_sizes, int n_in,
                              void* d_out, int out_size, void* d_ws, size_t ws_size,
                              hipStream_t stream)
{
    const float* X  = (const float*)d_in[0];
    // cultural path (d_in[1], d_in[8..10]) cancels in softmax -> unused
    const float* WQ = (const float*)d_in[2];
    const float* bQ = (const float*)d_in[3];
    const float* WK = (const float*)d_in[4];
    const float* bK = (const float*)d_in[5];
    const float* WV = (const float*)d_in[6];
    const float* bV = (const float*)d_in[7];

    char* ws = (char*)d_ws;
    _Float16* Qh  = (_Float16*)ws;  ws += (size_t)B_ * S_ * DK * 2;   // 2 MiB
    _Float16* Kh  = (_Float16*)ws;  ws += (size_t)B_ * S_ * DK * 2;
    _Float16* Vt  = (_Float16*)ws;  ws += (size_t)B_ * S_ * DK * 2;
    _Float16* Wt  = (_Float16*)ws;  ws += (size_t)3 * 64 * DM * 2;    // 384 KiB
    _Float16* Oph = (_Float16*)ws;  ws += (size_t)NSPLIT * B_ * S_ * DK * 2; // 16 MiB
    float* Lp     = (float*)ws;

    wt_kernel<<<dim3(DM / 64, 3), 256, 0, stream>>>(WQ, WK, WV, Wt);

    proj_mfma_kernel<<<dim3((B_ * S_) / 64), 256, 0, stream>>>(
        X, Wt, bQ, bK, bV, Qh, Kh, Vt);

    flash_mfma_kernel<<<dim3(S_ / QT, B_, NSPLIT), 512, 0, stream>>>(
        Qh, Kh, Vt, Oph, Lp);

    combine_kernel<<<dim3((B_ * S_) / 16), 256, 0, stream>>>(
        Oph, Lp, (float*)d_out);
}

// Round 9
// 151.245 us; speedup vs baseline: 1.0478x; 1.0133x over previous
//
#include <hip/hip_runtime.h>

#define B_  4
#define S_  4096
#define DM  1024
#define DK  64
#define NSPLIT 8
#define KSPAN (S_ / NSPLIT)
#define QT  256                  // queries per flash block

typedef _Float16 half8  __attribute__((ext_vector_type(8)));
typedef _Float16 half4v __attribute__((ext_vector_type(4)));
typedef __fp16   fp16x2 __attribute__((ext_vector_type(2)));   // cvt_pkrtz return type
typedef float    floatx4 __attribute__((ext_vector_type(4)));

// 0.125 (1/sqrt(64)) * log2(e): softmax in exp2 domain
#define QSCALE 0.18033688011112042f
#define EXP2F(x) __builtin_amdgcn_exp2f(x)

// ---------------------------------------------------------------------------
// One-time W transpose+convert: Wt[proj][n][k] f16  <-  W[k][n] fp32.
// ---------------------------------------------------------------------------
__global__ __launch_bounds__(256) void wt_kernel(
    const float* __restrict__ WQ, const float* __restrict__ WK,
    const float* __restrict__ WV, _Float16* __restrict__ Wt)
{
    const int proj = blockIdx.y;
    const float* W = (proj == 0) ? WQ : (proj == 1) ? WK : WV;
    const int k0 = blockIdx.x * 64;
    const int t = threadIdx.x;
    __shared__ float T[64][68];

    #pragma unroll
    for (int p = 0; p < 4; p++) {
        int c = p * 256 + t;
        int k = c >> 4, n4 = (c & 15) * 4;
        float4 v = *(const float4*)(W + (size_t)(k0 + k) * DK + n4);
        T[k][n4 + 0] = v.x; T[k][n4 + 1] = v.y;
        T[k][n4 + 2] = v.z; T[k][n4 + 3] = v.w;
    }
    __syncthreads();

    const int n = t >> 2, kc = (t & 3) * 16;
    half8 h0, h1;
    #pragma unroll
    for (int j = 0; j < 8; j++) h0[j] = (_Float16)T[kc + j][n];
    #pragma unroll
    for (int j = 0; j < 8; j++) h1[j] = (_Float16)T[kc + 8 + j][n];
    _Float16* dst = Wt + ((size_t)proj * 64 + n) * DM + k0 + kc;
    *(half8*)(dst)     = h0;
    *(half8*)(dst + 8) = h1;
}

// ---------------------------------------------------------------------------
// Proj v6: N-split-2. v1's exact fat-wave pipeline (4 waves x 16 rows,
// single-buffer, 2 barriers/step, 12 MFMA/wave/step) but each block owns
// HALF the N-columns (96) -> grid 512 = 2 independent blocks/CU. Unlike v4
// (which also went 2 blk/CU but shrank waves to 3 MFMA/step), per-wave
// latency tolerance is unchanged; the second block's pipeline fills this
// block's per-step stalls. W L2 traffic unchanged chip-wide; X staged 2x
// (L3-fed, cheap). LDS 23 KB.
// ---------------------------------------------------------------------------
__global__ __launch_bounds__(256) void proj_mfma_kernel(
    const float* __restrict__ X, const _Float16* __restrict__ Wt,
    const float* __restrict__ bQ, const float* __restrict__ bK,
    const float* __restrict__ bV,
    _Float16* __restrict__ Qh, _Float16* __restrict__ Kh,
    _Float16* __restrict__ Vt)
{
    const int r0   = blockIdx.x * 64;
    const int nh   = blockIdx.y;          // N-half: cols nh*96 .. nh*96+95
    const int t    = threadIdx.x;
    const int wave = t >> 6, lane = t & 63;
    const int quad = lane >> 4, l15 = lane & 15;

    __shared__ __align__(16) _Float16 Xs[64 * 72];        //  9 KB
    __shared__ __align__(16) _Float16 Ws[96 * 72];        // 13.5 KB

    const _Float16* Wb = Wt + (size_t)(nh * 96) * DM;

    floatx4 acc[6];
    #pragma unroll
    for (int j = 0; j < 6; j++) acc[j] = (floatx4){0.f, 0.f, 0.f, 0.f};

    int xrow[4], xcol[4];
    #pragma unroll
    for (int p = 0; p < 4; p++) {
        int c = p * 256 + t;
        xrow[p] = c >> 4; xcol[p] = (c & 15) * 4;
    }
    int wrow[3], wcol[3];                  // 96 rows x 64 cols = 3 half8/thread
    #pragma unroll
    for (int p = 0; p < 3; p++) {
        int c = p * 256 + t;
        wrow[p] = c >> 3; wcol[p] = (c & 7) * 8;
    }

    float4 xr[4]; half8 wr[3];
    #pragma unroll
    for (int p = 0; p < 4; p++)
        xr[p] = *(const float4*)(X + (size_t)(r0 + xrow[p]) * DM + xcol[p]);
    #pragma unroll
    for (int p = 0; p < 3; p++)
        wr[p] = *(const half8*)(Wb + (size_t)wrow[p] * DM + wcol[p]);

    for (int kt = 0; kt < DM / 64; kt++) {
        __syncthreads();
        #pragma unroll
        for (int p = 0; p < 4; p++) {
            half4v h;
            h[0] = (_Float16)xr[p].x; h[1] = (_Float16)xr[p].y;
            h[2] = (_Float16)xr[p].z; h[3] = (_Float16)xr[p].w;
            *(half4v*)&Xs[xrow[p] * 72 + xcol[p]] = h;
        }
        #pragma unroll
        for (int p = 0; p < 3; p++)
            *(half8*)&Ws[wrow[p] * 72 + wcol[p]] = wr[p];
        __syncthreads();

        if (kt + 1 < DM / 64) {
            const int kn = (kt + 1) * 64;
            #pragma unroll
            for (int p = 0; p < 4; p++)
                xr[p] = *(const float4*)(X + (size_t)(r0 + xrow[p]) * DM + kn + xcol[p]);
            #pragma unroll
            for (int p = 0; p < 3; p++)
                wr[p] = *(const half8*)(Wb + (size_t)wrow[p] * DM + kn + wcol[p]);
        }

        half8 xa0 = *(half8*)&Xs[(wave * 16 + l15) * 72 + quad * 8];
        half8 xa1 = *(half8*)&Xs[(wave * 16 + l15) * 72 + 32 + quad * 8];
        #pragma unroll
        for (int j = 0; j < 6; j++) {
            half8 bf0 = *(half8*)&Ws[(j * 16 + l15) * 72 + quad * 8];
            half8 bf1 = *(half8*)&Ws[(j * 16 + l15) * 72 + 32 + quad * 8];
            floatx4 a = acc[j];
            a = __builtin_amdgcn_mfma_f32_16x16x32_f16(xa0, bf0, a, 0, 0, 0);
            a = __builtin_amdgcn_mfma_f32_16x16x32_f16(xa1, bf1, a, 0, 0, 0);
            acc[j] = a;
        }
    }

    // epilogue: flat tile fg = nh*6+j in 0..11 -> proj = fg>>2, d-tile = fg&3
    const int orow = r0 + wave * 16 + quad * 4;
    const int bidx = r0 >> 12;
    const int s0   = (r0 & (S_ - 1)) + wave * 16 + quad * 4;

    if (nh == 0) {
        #pragma unroll
        for (int j = 0; j < 4; j++) {
            const int d = j * 16 + l15;
            const float bq = bQ[d];
            #pragma unroll
            for (int i = 0; i < 4; i++)
                Qh[(size_t)(orow + i) * DK + d] =
                    (_Float16)((acc[j][i] + bq) * QSCALE);
        }
        #pragma unroll
        for (int j = 4; j < 6; j++) {
            const int d = (j - 4) * 16 + l15;
            const float bk = bK[d];
            #pragma unroll
            for (int i = 0; i < 4; i++)
                Kh[(size_t)(orow + i) * DK + d] =
                    (_Float16)(acc[j][i] + bk);
        }
    } else {
        #pragma unroll
        for (int j = 0; j < 2; j++) {
            const int d = (2 + j) * 16 + l15;
            const float bk = bK[d];
            #pragma unroll
            for (int i = 0; i < 4; i++)
                Kh[(size_t)(orow + i) * DK + d] =
                    (_Float16)(acc[j][i] + bk);
        }
        #pragma unroll
        for (int j = 2; j < 6; j++) {
            const int d = (j - 2) * 16 + l15;
            const float bv = bV[d];
            half4v hv;
            #pragma unroll
            for (int i = 0; i < 4; i++)
                hv[i] = (_Float16)(acc[j][i] + bv);
            *(half4v*)(Vt + (size_t)bidx * DK * S_ + (size_t)d * S_ + s0) = hv;
        }
    }
}

// ---------------------------------------------------------------------------
// Flash v7: v6 (fused in-register softmax, slim regs) + setprio restored
// around both MFMA clusters (R8 dropped it and lost ~1.5us; m191: +4-7%).
// ---------------------------------------------------------------------------
__global__ __launch_bounds__(512, 4) void flash_mfma_kernel(
    const _Float16* __restrict__ Qh, const _Float16* __restrict__ Kh,
    const _Float16* __restrict__ Vt, _Float16* __restrict__ Oph,
    float* __restrict__ Lp)
{
    const int b     = blockIdx.y;
    const int q0    = blockIdx.x * QT;
    const int split = blockIdx.z;
    const int kbase = split * KSPAN;
    const int t     = threadIdx.x;
    const int wave  = t >> 6, lane = t & 63;
    const int quad  = lane >> 4, l15 = lane & 15;

    __shared__ __align__(16) _Float16 Ks[2][64 * 72];     // key-permuted rows
    __shared__ __align__(16) _Float16 Vs[2][64 * 72];     // [d][key]

    const _Float16* Qb = Qh + ((size_t)b * S_ + q0) * DK;
    const _Float16* Kb = Kh + ((size_t)b * S_ + kbase) * DK;
    const _Float16* Vb = Vt + (size_t)b * DK * S_ + kbase;

    half8 qf0[2], qf1[2];
    #pragma unroll
    for (int mt = 0; mt < 2; mt++) {
        const _Float16* qr = Qb + (size_t)(wave * 32 + mt * 16 + l15) * DK;
        qf0[mt] = *(const half8*)(qr + quad * 8);
        qf1[mt] = *(const half8*)(qr + 32 + quad * 8);
    }

    floatx4 acc[2][4];
    float rs[2];
    #pragma unroll
    for (int mt = 0; mt < 2; mt++) {
        #pragma unroll
        for (int nt = 0; nt < 4; nt++) acc[mt][nt] = (floatx4){0.f,0.f,0.f,0.f};
        rs[mt] = 0.f;
    }

    const int kr   = t >> 3, kcol = (t & 7) * 8;
    const int krP  = (kr & 32) | ((kr & 4) << 2) | ((kr & 24) >> 1) | (kr & 3);
    half8 kreg = *(const half8*)(Kb + (size_t)kr * DK + kcol);
    half8 vreg = *(const half8*)(Vb + (size_t)kr * S_ + kcol);
    *(half8*)&Ks[0][krP * 72 + kcol] = kreg;
    *(half8*)&Vs[0][kr  * 72 + kcol] = vreg;

    const int NT = KSPAN / 64;
    int cur = 0;
    for (int it = 0; it < NT; it++) {
        __syncthreads();     // buf[cur] ready; everyone done with buf[cur^1]

        if (it + 1 < NT) {
            const int kn = (it + 1) * 64;
            kreg = *(const half8*)(Kb + (size_t)(kn + kr) * DK + kcol);
            vreg = *(const half8*)(Vb + (size_t)kr * S_ + kn + kcol);
        }

        // QK^T fused with softmax numerator: each z consumed immediately
        half8 pf0[2], pf1[2];
        __builtin_amdgcn_s_setprio(1);
        #pragma unroll
        for (int nt = 0; nt < 4; nt++) {
            half8 kf0 = *(half8*)&Ks[cur][(nt * 16 + l15) * 72 + quad * 8];
            half8 kf1 = *(half8*)&Ks[cur][(nt * 16 + l15) * 72 + 32 + quad * 8];
            #pragma unroll
            for (int mt = 0; mt < 2; mt++) {
                floatx4 z = (floatx4){0.f, 0.f, 0.f, 0.f};
                z = __builtin_amdgcn_mfma_f32_16x16x32_f16(kf0, qf0[mt], z, 0, 0, 0);
                z = __builtin_amdgcn_mfma_f32_16x16x32_f16(kf1, qf1[mt], z, 0, 0, 0);
                float p0 = EXP2F(z[0]), p1 = EXP2F(z[1]);
                float p2 = EXP2F(z[2]), p3 = EXP2F(z[3]);
                rs[mt] += p0; rs[mt] += p1; rs[mt] += p2; rs[mt] += p3;
                fp16x2 ca = __builtin_amdgcn_cvt_pkrtz(p0, p1);
                fp16x2 cb = __builtin_amdgcn_cvt_pkrtz(p2, p3);
                if (nt < 2) {
                    pf0[mt][(nt & 1) * 4 + 0] = (_Float16)ca[0];
                    pf0[mt][(nt & 1) * 4 + 1] = (_Float16)ca[1];
                    pf0[mt][(nt & 1) * 4 + 2] = (_Float16)cb[0];
                    pf0[mt][(nt & 1) * 4 + 3] = (_Float16)cb[1];
                } else {
                    pf1[mt][(nt & 1) * 4 + 0] = (_Float16)ca[0];
                    pf1[mt][(nt & 1) * 4 + 1] = (_Float16)ca[1];
                    pf1[mt][(nt & 1) * 4 + 2] = (_Float16)cb[0];
                    pf1[mt][(nt & 1) * 4 + 3] = (_Float16)cb[1];
                }
            }
        }
        __builtin_amdgcn_s_setprio(0);

        // O^T += V^T·P^T
        __builtin_amdgcn_s_setprio(1);
        #pragma unroll
        for (int nt = 0; nt < 4; nt++) {
            half8 vf0 = *(half8*)&Vs[cur][(nt * 16 + l15) * 72 + quad * 8];
            half8 vf1 = *(half8*)&Vs[cur][(nt * 16 + l15) * 72 + 32 + quad * 8];
            #pragma unroll
            for (int mt = 0; mt < 2; mt++) {
                floatx4 a = acc[mt][nt];
                a = __builtin_amdgcn_mfma_f32_16x16x32_f16(vf0, pf0[mt], a, 0, 0, 0);
                a = __builtin_amdgcn_mfma_f32_16x16x32_f16(vf1, pf1[mt], a, 0, 0, 0);
                acc[mt][nt] = a;
            }
        }
        __builtin_amdgcn_s_setprio(0);

        if (it + 1 < NT) {
            *(half8*)&Ks[cur ^ 1][krP * 72 + kcol] = kreg;
            *(half8*)&Vs[cur ^ 1][kr  * 72 + kcol] = vreg;
        }
        cur ^= 1;
    }

    const size_t prow = (size_t)split * B_ * S_ + (size_t)b * S_ + q0;
    #pragma unroll
    for (int mt = 0; mt < 2; mt++) {
        float r = rs[mt];
        r += __shfl_xor(r, 16, 64);
        r += __shfl_xor(r, 32, 64);
        const float inv = 1.0f / r;
        const size_t orow = prow + wave * 32 + mt * 16 + l15;
        #pragma unroll
        for (int nt = 0; nt < 4; nt++) {
            half4v hv;
            #pragma unroll
            for (int i = 0; i < 4; i++)
                hv[i] = (_Float16)(acc[mt][nt][i] * inv);
            *(half4v*)(Oph + orow * DK + nt * 16 + quad * 4) = hv;
        }
        if (quad == 0)
            Lp[orow] = r;
    }
}

// ---------------------------------------------------------------------------
// Combine: O[r] = sum_s l_s * Ohat_s[r] / sum_s l_s.  16 rows x 16 lanes.
// ---------------------------------------------------------------------------
__global__ __launch_bounds__(256) void combine_kernel(
    const _Float16* __restrict__ Oph, const float* __restrict__ Lp,
    float* __restrict__ O)
{
    const int r  = blockIdx.x * 16 + (threadIdx.x >> 4);
    const int d4 = (threadIdx.x & 15) * 4;
    const int NR = B_ * S_;

    float lw[NSPLIT], lsum = 0.f;
    #pragma unroll
    for (int s = 0; s < NSPLIT; s++) {
        lw[s] = Lp[(size_t)s * NR + r];
        lsum += lw[s];
    }
    const float inv = 1.0f / lsum;

    float o[4] = {0.f, 0.f, 0.f, 0.f};
    #pragma unroll
    for (int s = 0; s < NSPLIT; s++) {
        half4v h = *(const half4v*)(Oph + ((size_t)s * NR + r) * DK + d4);
        const float w = lw[s];
        #pragma unroll
        for (int j = 0; j < 4; j++) o[j] += w * (float)h[j];
    }
    float4 out;
    out.x = o[0] * inv; out.y = o[1] * inv;
    out.z = o[2] * inv; out.w = o[3] * inv;
    *(float4*)(O + (size_t)r * DK + d4) = out;
}

// ---------------------------------------------------------------------------
extern "C" void kernel_launch(void* const* d_in, const int* in_sizes, int n_in,
                              void* d_out, int out_size, void* d_ws, size_t ws_size,
                              hipStream_t stream)
{
    const float* X  = (const float*)d_in[0];
    // cultural path (d_in[1], d_in[8..10]) cancels in softmax -> unused
    const float* WQ = (const float*)d_in[2];
    const float* bQ = (const float*)d_in[3];
    const float* WK = (const float*)d_in[4];
    const float* bK = (const float*)d_in[5];
    const float* WV = (const float*)d_in[6];
    const float* bV = (const float*)d_in[7];

    char* ws = (char*)d_ws;
    _Float16* Qh  = (_Float16*)ws;  ws += (size_t)B_ * S_ * DK * 2;   // 2 MiB
    _Float16* Kh  = (_Float16*)ws;  ws += (size_t)B_ * S_ * DK * 2;
    _Float16* Vt  = (_Float16*)ws;  ws += (size_t)B_ * S_ * DK * 2;
    _Float16* Wt  = (_Float16*)ws;  ws += (size_t)3 * 64 * DM * 2;    // 384 KiB
    _Float16* Oph = (_Float16*)ws;  ws += (size_t)NSPLIT * B_ * S_ * DK * 2; // 16 MiB
    float* Lp     = (float*)ws;

    wt_kernel<<<dim3(DM / 64, 3), 256, 0, stream>>>(WQ, WK, WV, Wt);

    proj_mfma_kernel<<<dim3((B_ * S_) / 64, 2), 256, 0, stream>>>(
        X, Wt, bQ, bK, bV, Qh, Kh, Vt);

    flash_mfma_kernel<<<dim3(S_ / QT, B_, NSPLIT), 512, 0, stream>>>(
        Qh, Kh, Vt, Oph, Lp);

    combine_kernel<<<dim3((B_ * S_) / 16), 256, 0, stream>>>(
        Oph, Lp, (float*)d_out);
}